// Round 1
// baseline (16424.849 us; speedup 1.0000x reference)
//
#include <hip/hip_runtime.h>
#include <math.h>

// Problem constants (from reference): B=4, H=16, S=2048, D=64
constexpr int S  = 2048;
constexpr int D  = 64;
constexpr int BH = 64;          // B*H
constexpr float SCALE = 0.125f; // 1/sqrt(64)

constexpr int TQ_A = 32;   // q rows per block, scores kernel
constexpr int TK   = 128;  // k rows per tile
constexpr int NKT  = S / TK;
constexpr int KS   = D + 4;   // 68: LDS row stride for K/V tiles (keeps 16B align)
constexpr int TQ_B = 64;   // q rows per block, pv kernel
constexpr int CS   = TK + 4;  // 132: LDS row stride for score tile (16B align)

// ---------------- Kernel A: raw scores + online softmax stats ----------------
// grid: (S/TQ_A, BH), block 256
__global__ __launch_bounds__(256, 3)
void attn_scores_kernel(const float* __restrict__ Q, const float* __restrict__ K,
                        const float* __restrict__ MASK, float* __restrict__ Wraw,
                        float* __restrict__ stats)
{
    const int t  = threadIdx.x;
    const int q0 = blockIdx.x * TQ_A;
    const int bh = blockIdx.y;

    __shared__ float qs[TQ_A][D];
    __shared__ float ks[TK][KS];
    __shared__ float rowm[TQ_A];
    __shared__ float rowl[TQ_A];

    // load Q tile (32x64 = 512 float4)
    const float* qbase = Q + ((size_t)bh * S + q0) * D;
    for (int i = t; i < TQ_A * D / 4; i += 256) {
        float4 v = ((const float4*)qbase)[i];
        int r = i >> 4, c = (i & 15) << 2;
        *(float4*)&qs[r][c] = v;
    }
    if (t < TQ_A) { rowm[t] = -3.0e38f; rowl[t] = 0.0f; }

    const int qg = t >> 5;   // 0..7  : q-row group (half-wave uniform)
    const int kc = t & 31;   // 0..31 : k column within half-wave

    for (int kt = 0; kt < NKT; ++kt) {
        const int k0 = kt * TK;
        __syncthreads();   // protects ks reuse + rowm/rowl init
        const float* kbase = K + ((size_t)bh * S + k0) * D;
        for (int i = t; i < TK * D / 4; i += 256) {
            float4 v = ((const float4*)kbase)[i];
            int r = i >> 4, c = (i & 15) << 2;
            *(float4*)&ks[r][c] = v;
        }
        __syncthreads();

        // 4q x 4k register micro-tile, k strided by 32 for LDS bank spread
        float acc[4][4];
        #pragma unroll
        for (int a = 0; a < 4; ++a)
            #pragma unroll
            for (int b = 0; b < 4; ++b) acc[a][b] = 0.0f;

        #pragma unroll
        for (int dc = 0; dc < D; dc += 4) {
            float4 qv[4], kv[4];
            #pragma unroll
            for (int a = 0; a < 4; ++a) qv[a] = *(const float4*)&qs[qg + 8*a][dc];
            #pragma unroll
            for (int b = 0; b < 4; ++b) kv[b] = *(const float4*)&ks[kc + 32*b][dc];
            #pragma unroll
            for (int a = 0; a < 4; ++a)
                #pragma unroll
                for (int b = 0; b < 4; ++b)
                    acc[a][b] += qv[a].x*kv[b].x + qv[a].y*kv[b].y
                               + qv[a].z*kv[b].z + qv[a].w*kv[b].w;
        }

        // scale + mask, write raw scores, update per-row online (m,l)
        #pragma unroll
        for (int a = 0; a < 4; ++a) {
            const int qrow  = qg + 8*a;            // owned exclusively by this half-wave
            const int qglob = q0 + qrow;
            float s[4];
            #pragma unroll
            for (int b = 0; b < 4; ++b) {
                const int kglob = k0 + kc + 32*b;
                s[b] = acc[a][b] * SCALE + MASK[(size_t)qglob * S + kglob];
                Wraw[((size_t)bh * S + qglob) * S + kglob] = s[b];
            }
            float lmax = fmaxf(fmaxf(s[0], s[1]), fmaxf(s[2], s[3]));
            #pragma unroll
            for (int off = 16; off >= 1; off >>= 1)
                lmax = fmaxf(lmax, __shfl_xor(lmax, off));   // xor<32 stays in half-wave
            const float m_old = rowm[qrow];
            const float m_new = fmaxf(m_old, lmax);
            float esum = __expf(s[0]-m_new) + __expf(s[1]-m_new)
                       + __expf(s[2]-m_new) + __expf(s[3]-m_new);
            #pragma unroll
            for (int off = 16; off >= 1; off >>= 1)
                esum += __shfl_xor(esum, off);
            if (kc == 0) {   // wave-lockstep: all lanes read rowm before this write
                rowl[qrow] = rowl[qrow] * __expf(m_old - m_new) + esum;
                rowm[qrow] = m_new;
            }
        }
    }

    __syncthreads();
    if (t < TQ_A) {
        const size_t r = (size_t)bh * S + q0 + t;
        stats[2*r]   = rowm[t];
        stats[2*r+1] = rowl[t];
    }
}

// ---------------- Kernel B: normalize weights + P.V ----------------
// grid: (S/TQ_B, BH), block 256
__global__ __launch_bounds__(256, 2)
void attn_norm_pv_kernel(const float* __restrict__ V, const float* __restrict__ stats,
                         float* __restrict__ W, float* __restrict__ Out)
{
    const int t  = threadIdx.x;
    const int q0 = blockIdx.x * TQ_B;
    const int bh = blockIdx.y;

    __shared__ float vs[TK][KS];
    __shared__ float sc[TQ_B][CS];
    __shared__ float rm[TQ_B];
    __shared__ float rl[TQ_B];

    if (t < TQ_B) {
        const size_t r = (size_t)bh * S + q0 + t;
        rm[t] = stats[2*r];
        rl[t] = 1.0f / stats[2*r+1];
    }
    __syncthreads();

    const int d4   = (t & 15) << 2;  // d chunk base (0,4,...,60)
    const int qsel = t >> 4;         // 0..15

    float a0[4] = {0,0,0,0}, a1[4] = {0,0,0,0}, a2[4] = {0,0,0,0}, a3[4] = {0,0,0,0};

    for (int kt = 0; kt < NKT; ++kt) {
        const int k0 = kt * TK;
        // V tile -> LDS
        const float* vbase = V + ((size_t)bh * S + k0) * D;
        for (int i = t; i < TK * D / 4; i += 256) {
            float4 v = ((const float4*)vbase)[i];
            int r = i >> 4, c = (i & 15) << 2;
            *(float4*)&vs[r][c] = v;
        }
        // raw scores -> weights (gmem) + LDS stage
        #pragma unroll
        for (int jj = 0; jj < 8; ++jj) {
            const int i4  = t + 256*jj;
            const int row = i4 >> 5, c = (i4 & 31) << 2;
            const size_t g = ((size_t)bh*S + q0 + row)*S + k0 + c;
            float4 sv = *(const float4*)&W[g];
            const float m = rm[row], irl = rl[row];
            float4 wv;
            wv.x = __expf(sv.x - m) * irl;
            wv.y = __expf(sv.y - m) * irl;
            wv.z = __expf(sv.z - m) * irl;
            wv.w = __expf(sv.w - m) * irl;
            *(float4*)&W[g] = wv;
            *(float4*)&sc[row][c] = wv;
        }
        __syncthreads();

        // PV: 4q x 4d per thread over this k tile
        #pragma unroll 4
        for (int kk = 0; kk < TK; ++kk) {
            const float4 vv = *(const float4*)&vs[kk][d4];
            const float w0 = sc[qsel     ][kk];
            const float w1 = sc[qsel + 16][kk];
            const float w2 = sc[qsel + 32][kk];
            const float w3 = sc[qsel + 48][kk];
            a0[0] += w0*vv.x; a0[1] += w0*vv.y; a0[2] += w0*vv.z; a0[3] += w0*vv.w;
            a1[0] += w1*vv.x; a1[1] += w1*vv.y; a1[2] += w1*vv.z; a1[3] += w1*vv.w;
            a2[0] += w2*vv.x; a2[1] += w2*vv.y; a2[2] += w2*vv.z; a2[3] += w2*vv.w;
            a3[0] += w3*vv.x; a3[1] += w3*vv.y; a3[2] += w3*vv.z; a3[3] += w3*vv.w;
        }
        __syncthreads();  // protect vs/sc overwrite next iter
    }

    const size_t ob = (size_t)bh*S + q0;
    *(float4*)&Out[(ob + qsel     )*D + d4] = make_float4(a0[0],a0[1],a0[2],a0[3]);
    *(float4*)&Out[(ob + qsel + 16)*D + d4] = make_float4(a1[0],a1[1],a1[2],a1[3]);
    *(float4*)&Out[(ob + qsel + 32)*D + d4] = make_float4(a2[0],a2[1],a2[2],a2[3]);
    *(float4*)&Out[(ob + qsel + 48)*D + d4] = make_float4(a3[0],a3[1],a3[2],a3[3]);
}

extern "C" void kernel_launch(void* const* d_in, const int* in_sizes, int n_in,
                              void* d_out, int out_size, void* d_ws, size_t ws_size,
                              hipStream_t stream) {
    const float* q    = (const float*)d_in[0];
    const float* k    = (const float*)d_in[1];
    const float* v    = (const float*)d_in[2];
    const float* mask = (const float*)d_in[3];

    float* out      = (float*)d_out;
    float* attended = out;                        // [BH, S, D]
    float* weights  = out + (size_t)BH * S * D;   // [BH, S, S]
    float* stats    = (float*)d_ws;               // [BH*S][2] = 1 MB of d_ws

    dim3 blk(256);
    attn_scores_kernel<<<dim3(S/TQ_A, BH), blk, 0, stream>>>(q, k, mask, weights, stats);
    attn_norm_pv_kernel<<<dim3(S/TQ_B, BH), blk, 0, stream>>>(v, stats, weights, attended);
}